// Round 14
// baseline (3401.281 us; speedup 1.0000x reference)
//
#include <hip/hip_runtime.h>
#include <hip/hip_bf16.h>

#define NSEQ 320
#define NTRAN 256
#define TT 128
#define TDOC 256
#define EH 512
#define XR_TRAN (NTRAN*TT)            // 32768
#define XROWS (XR_TRAN + 64*TDOC)     // 49152
#define HSLOTS 6
#define FW 264

typedef __attribute__((ext_vector_type(8))) short bf16x8v;
typedef __attribute__((ext_vector_type(4))) float f32x4v;

// ---- module-global scratch ----
__device__ __align__(16) unsigned short g_xb [(size_t)XROWS*EH];     // bf16 embeddings
__device__ __align__(16) unsigned short g_wbx[2*2048*512];           // bf16 wih [path][col][k]
__device__ __align__(16) unsigned short g_w2b[2*5*512*512];          // bf16 recurrence W [path][cg][k][col]
__device__ float g_xp[(size_t)XROWS*2048];  // xproj+bias, gate-interleaved cols (fp32)
__device__ float g_h [HSLOTS*NSEQ*EH];      // h ring — system-scope accessed
__device__ float g_sc[64*260];              // doc scores
__device__ float g_pool[NSEQ*EH];
__device__ float g_loss;
__device__ unsigned g_gflag[48*FW];
__device__ unsigned g_sflag[16*FW];
__device__ unsigned g_aprog[48];

__device__ __forceinline__ float sigm(float x) { return 1.0f / (1.0f + expf(-x)); }

__device__ __forceinline__ float ldg_sys(const float* p) {
  return __hip_atomic_load(p, __ATOMIC_RELAXED, __HIP_MEMORY_SCOPE_SYSTEM);
}
__device__ __forceinline__ void stg_sys(float* p, float v) {
  __hip_atomic_store(p, v, __ATOMIC_RELAXED, __HIP_MEMORY_SCOPE_SYSTEM);
}
__device__ __forceinline__ unsigned ldu(const unsigned* p) {
  return __hip_atomic_load(p, __ATOMIC_RELAXED, __HIP_MEMORY_SCOPE_AGENT);
}
__device__ __forceinline__ unsigned short f2b(float f) {
  __hip_bfloat16 h = __float2bfloat16(f);
  return *reinterpret_cast<unsigned short*>(&h);
}

// ---------------- init per call ----------------
__global__ __launch_bounds__(256) void init_state() {
  int i = blockIdx.x*256 + threadIdx.x;
  if (i < NSEQ*EH) g_h[5*NSEQ*EH + i] = 0.0f;
  if (i < 64*260) g_sc[i] = 0.0f;
  if (i < 48*FW) g_gflag[i] = 0u;
  if (i < 16*FW) g_sflag[i] = 0u;
  if (i < 48) g_aprog[i] = 0u;
  if (i == 0) g_loss = 0.0f;
}

// ---------------- bf16 xproj weights ----------------
__global__ __launch_bounds__(256) void build_wbx(
    const float* __restrict__ wih_t, const float* __restrict__ wih_d) {
  int idx = blockIdx.x*256 + threadIdx.x;
  if (idx >= 2*2048*512) return;
  int p = idx / (2048*512); int rem = idx % (2048*512);
  const float* wih = p ? wih_d : wih_t;
  g_wbx[idx] = f2b(wih[rem]);
}

// ---------------- bf16 recurrence weights: [path][cg][k][col512] ----------------
__global__ __launch_bounds__(256) void build_wt2(
    const float* __restrict__ whh_t, const float* __restrict__ whh_d,
    const float* __restrict__ aw_t,  const float* __restrict__ aw_d) {
  int idx = blockIdx.x*256 + threadIdx.x;
  if (idx >= 2*5*512*512) return;
  int p  = idx / (5*512*512); int rem = idx % (5*512*512);
  int cg = rem / (512*512);   int r2  = rem % (512*512);
  int k  = r2 >> 9;           int c   = r2 & 511;
  float v;
  if (cg < 4) {
    int r = (c >> 7)*512 + cg*128 + (c & 127);
    const float* whh = p ? whh_d : whh_t;
    v = whh[r*512 + k];
  } else {
    const float* aw = p ? aw_d : aw_t;
    v = aw[c*512 + k];
  }
  g_w2b[((size_t)(p*5 + cg)*512 + k)*512 + c] = f2b(v);
}

// ---------------- pre-gather embeddings -> bf16 ----------------
__global__ __launch_bounds__(128) void pregather(
    const int* __restrict__ tran, const int* __restrict__ da_tok,
    const int* __restrict__ dn_tok, const float* __restrict__ emb) {
  int row = blockIdx.x;
  int tok;
  if (row < XR_TRAN) tok = tran[row];
  else {
    int q = row - XR_TRAN;
    tok = (q < 32*TDOC) ? da_tok[q] : dn_tok[q - 32*TDOC];
  }
  const float4* src = (const float4*)&emb[(size_t)tok*EH];
  float4 v = src[threadIdx.x];
  uint2 o;
  o.x = (unsigned)f2b(v.x) | ((unsigned)f2b(v.y) << 16);
  o.y = (unsigned)f2b(v.z) | ((unsigned)f2b(v.w) << 16);
  ((uint2*)&g_xb[(size_t)row*EH])[threadIdx.x] = o;
}

// ---------------- MFMA bf16 xproj (unchanged from R13) ----------------
__global__ __launch_bounds__(512, 2) void xproj_mfma(
    const float* __restrict__ b_t, const float* __restrict__ b_d) {
  __shared__ short As[2][256*32];
  __shared__ short Bs[2][256*32];
  const int bid = blockIdx.x;
  const int mt = bid >> 3, ntb = bid & 7;
  const size_t mb = (size_t)mt * 256; const int nb = ntb * 256;
  const bool tp = (mb < XR_TRAN);
  const size_t wboff = (tp ? 0 : (size_t)2048*512);
  const float* __restrict__ bias = tp ? b_t : b_d;
  const int tid = threadIdx.x;
  const int l = tid & 63, w = tid >> 6;
  const int mw = w >> 2, nw = w & 3;

  f32x4v acc[8][4];
  #pragma unroll
  for (int m2 = 0; m2 < 8; ++m2)
    #pragma unroll
    for (int n2 = 0; n2 < 4; ++n2) acc[m2][n2] = (f32x4v){0.f, 0.f, 0.f, 0.f};

  uint4 rA[2], rB[2];
  auto stage_load = [&](int k0) {
    #pragma unroll
    for (int i = 0; i < 2; ++i) {
      int u = i*512 + tid;
      rA[i] = *(const uint4*)&g_xb[(mb + (u >> 2))*512 + k0 + (u & 3)*8];
      rB[i] = *(const uint4*)&g_wbx[wboff + (size_t)(nb + (u >> 2))*512 + k0 + (u & 3)*8];
    }
  };
  auto stage_write = [&](int buf) {
    #pragma unroll
    for (int i = 0; i < 2; ++i) {
      int u = i*512 + tid;
      *(uint4*)&As[buf][u*8] = rA[i];
      *(uint4*)&Bs[buf][u*8] = rB[i];
    }
  };

  stage_load(0); stage_write(0); __syncthreads();
  for (int ks = 0; ks < 16; ++ks) {
    const int buf = ks & 1;
    if (ks < 15) stage_load((ks + 1)*32);
    bf16x8v aF[8], bF[4];
    #pragma unroll
    for (int m2 = 0; m2 < 8; ++m2)
      aF[m2] = *(const bf16x8v*)&As[buf][(mw*128 + m2*16 + (l & 15))*32 + (l >> 4)*8];
    #pragma unroll
    for (int n2 = 0; n2 < 4; ++n2)
      bF[n2] = *(const bf16x8v*)&Bs[buf][(nw*64 + n2*16 + (l & 15))*32 + (l >> 4)*8];
    #pragma unroll
    for (int m2 = 0; m2 < 8; ++m2)
      #pragma unroll
      for (int n2 = 0; n2 < 4; ++n2)
        acc[m2][n2] = __builtin_amdgcn_mfma_f32_16x16x32_bf16(aF[m2], bF[n2], acc[m2][n2], 0, 0, 0);
    __syncthreads();
    if (ks < 15) stage_write(buf ^ 1);
    __syncthreads();
  }

  #pragma unroll
  for (int n2 = 0; n2 < 4; ++n2) {
    const int colg = nb + nw*64 + n2*16 + (l & 15);
    const int col2 = ((colg & 511) >> 7)*512 + (colg >> 9)*128 + (colg & 127);
    const float bv = bias[colg];
    #pragma unroll
    for (int m2 = 0; m2 < 8; ++m2) {
      #pragma unroll
      for (int r = 0; r < 4; ++r) {
        size_t row = mb + mw*128 + m2*16 + (l >> 4)*4 + r;
        g_xp[row*2048 + col2] = acc[m2][n2][r] + bv;
      }
    }
  }
}

// ---------------- recurrence GEMM: wave=kq(0..7, 64k); per-lane col offset ----------
// wpl: weight ptr already offset to this lane's first col (stride 512 per k).
// clbase: this lane's linear partial-column index. PW = CPL*64+4.
template<int S, int CPL>
__device__ __forceinline__ void gemm2(const unsigned short* __restrict__ wpl,
                                      const float* __restrict__ ht,
                                      float* __restrict__ part,
                                      int kq, int clbase) {
  constexpr int PW = CPL*64 + 4;
  float acc[CPL][S];
  #pragma unroll
  for (int c = 0; c < CPL; ++c)
    #pragma unroll
    for (int s = 0; s < S; ++s) acc[c][s] = 0.0f;
  const unsigned short* wp = wpl + (size_t)(kq*64)*512;
  const float* hb = ht + kq*64;
  #pragma unroll 2
  for (int k4 = 0; k4 < 16; ++k4) {
    float4 hv[S];
    #pragma unroll
    for (int s = 0; s < S; ++s) hv[s] = *(const float4*)&hb[s*516 + k4*4];
    #pragma unroll
    for (int i4 = 0; i4 < 4; ++i4) {
      float wf[CPL];
      if constexpr (CPL == 8) {
        uint4 wv = *(const uint4*)(wp + (size_t)(k4*4 + i4)*512);
        wf[0] = __uint_as_float(wv.x << 16); wf[1] = __uint_as_float(wv.x & 0xFFFF0000u);
        wf[2] = __uint_as_float(wv.y << 16); wf[3] = __uint_as_float(wv.y & 0xFFFF0000u);
        wf[4] = __uint_as_float(wv.z << 16); wf[5] = __uint_as_float(wv.z & 0xFFFF0000u);
        wf[6] = __uint_as_float(wv.w << 16); wf[7] = __uint_as_float(wv.w & 0xFFFF0000u);
      } else if constexpr (CPL == 4) {
        uint2 wv = *(const uint2*)(wp + (size_t)(k4*4 + i4)*512);
        wf[0] = __uint_as_float(wv.x << 16); wf[1] = __uint_as_float(wv.x & 0xFFFF0000u);
        wf[2] = __uint_as_float(wv.y << 16); wf[3] = __uint_as_float(wv.y & 0xFFFF0000u);
      } else {
        unsigned wv = *(const unsigned*)(wp + (size_t)(k4*4 + i4)*512);
        wf[0] = __uint_as_float(wv << 16); wf[1] = __uint_as_float(wv & 0xFFFF0000u);
      }
      #pragma unroll
      for (int s = 0; s < S; ++s) {
        float h = ((const float*)&hv[s])[i4];
        #pragma unroll
        for (int c = 0; c < CPL; ++c) acc[c][s] = fmaf(wf[c], h, acc[c][s]);
      }
    }
  }
  if (kq < 4) {
    #pragma unroll
    for (int s = 0; s < S; ++s)
      #pragma unroll
      for (int c = 0; c < CPL; ++c)
        part[(size_t)(kq*S + s)*PW + clbase + c] = acc[c][s];
  }
  __syncthreads();
  if (kq >= 4) {
    const int q = kq - 4;
    #pragma unroll
    for (int s = 0; s < S; ++s)
      #pragma unroll
      for (int c = 0; c < CPL; ++c)
        part[(size_t)(q*S + s)*PW + clbase + c] += acc[c][s];
  }
}

// ---------------- persistent recurrence kernel ----------------
// tran (x<5): 32 groups x (4 gate 512col + 1 attn 512col), S=8, 128 steps. [unchanged]
// doc (x 5..7): slot=(x-5)*32+m in 0..95 = 8 groups x 12 blocks: role=slot%12:
//   role<8: gate, cg=role>>1, half=role&1 — 256 cols = (4 gates x 64 j, strided map)
//   role>=8: attn quarter q4=role-8 — 128 cols/dims.  S=8, 256 steps.
// Sync: per-group monotonic flags, relaxed L3 atomics (no fences; L2 stays warm).
__global__ __launch_bounds__(512, 2) void persist(
    const int* __restrict__ tbl, const int* __restrict__ dal, const int* __restrict__ dnl,
    const float* __restrict__ ab_t, const float* __restrict__ ab_d,
    const float* __restrict__ sw_t, const float* __restrict__ sw_d,
    const float* __restrict__ sb_t, const float* __restrict__ sb_d) {
  __shared__ float sm[28920];   // 115.7 KB -> 1 block/CU
  float* part = sm;             // up to [4][8][516] = 16512
  float* ht   = sm + 16512;     // [8][516]
  float* cb   = sm + 20640;     // 4096
  float* scr  = sm + 24736;
  float* ml   = sm + 24752;
  float* lenb = sm + 24768;
  float* alb  = sm + 24776;
  float* htB  = sm + 24792;     // [8][516] attn ping-pong

  const int b = blockIdx.x, tid = threadIdx.x;
  const int x = b & 7, m = b >> 3;
  const bool tran = (x < 5);
  const int S = 8;
  int gr, sbase, Ts, grd = 0, cgx = 0, halfx = 0, q4 = 0;
  bool isattn;
  unsigned GN, AK;
  if (tran) {
    gr = m; sbase = m*8; Ts = TT; GN = 4u; AK = 1u;
    isattn = (x == 4); cgx = x;
  } else {
    int slot = (x - 5)*32 + m; grd = slot / 12; int role = slot % 12;
    gr = 32 + grd; sbase = NTRAN + grd*8; Ts = TDOC; GN = 8u; AK = 4u;
    isattn = (role >= 8);
    if (!isattn) { cgx = role >> 1; halfx = role & 1; } else { q4 = role - 8; }
  }
  const int wslice = tran ? (isattn ? 4 : cgx) : (5 + (isattn ? 4 : cgx));
  const unsigned short* __restrict__ wbase = g_w2b + (size_t)wslice*512*512;
  const float* __restrict__ ab = tran ? ab_t : ab_d;
  const float* __restrict__ sw = tran ? sw_t : sw_d;
  const float  sb = tran ? sb_t[0] : sb_d[0];

  const int lane = tid & 63, kq = tid >> 6;
  const int w = kq;
  // per-lane column mapping
  int coloff, clbase;
  if (tran)            { coloff = lane*8;                                    clbase = lane*8; }
  else if (!isattn)    { coloff = (lane>>4)*128 + halfx*64 + (lane&15)*4;    clbase = (lane>>4)*64 + (lane&15)*4; }
  else                 { coloff = q4*128 + lane*2;                           clbase = lane*2; }
  const unsigned short* __restrict__ wpl = wbase + coloff;
  const int PW = tran ? 516 : (isattn ? 132 : 260);
  const int CW = isattn ? (tran ? 512 : 128) : 0;
  const int DW = CW;
  const int colbase = isattn ? (tran ? 0 : q4*128) : 0;

  for (int i = tid; i < 4096; i += 512) cb[i] = 0.0f;
  if (tid < S) {
    ml[tid*2] = -3.0e38f; ml[tid*2+1] = 0.0f;
    int s = sbase + tid;
    int len = tran ? tbl[s] : (s < NTRAN+32 ? dal[s-NTRAN] : dnl[s-NTRAN-32]);
    lenb[tid] = (float)len;
  }
  __syncthreads();

  if (!isattn) {
    // ================= gate block =================
    for (int t = 0; t < Ts; ++t) {
      float xpA[4], xpB[4];
      if (tran) {
        { int i = tid; int jl = i & 127, s = i >> 7;
          size_t row = (size_t)(sbase + s)*TT + t;
          const float* xr = &g_xp[row*2048 + cgx*512];
          #pragma unroll
          for (int g4 = 0; g4 < 4; ++g4) xpA[g4] = xr[g4*128 + jl]; }
        { int i = tid + 512; int jl = i & 127, s = i >> 7;
          size_t row = (size_t)(sbase + s)*TT + t;
          const float* xr = &g_xp[row*2048 + cgx*512];
          #pragma unroll
          for (int g4 = 0; g4 < 4; ++g4) xpB[g4] = xr[g4*128 + jl]; }
      } else {
        int jl = tid & 63, s = tid >> 6;
        size_t row = (size_t)XR_TRAN + (size_t)(sbase + s - NTRAN)*TDOC + t;
        const float* xr = &g_xp[row*2048 + cgx*512 + halfx*64];
        #pragma unroll
        for (int g4 = 0; g4 < 4; ++g4) xpA[g4] = xr[g4*128 + jl];
      }
      if (tid == 0) {
        if (t > 0)
          while (ldu(&g_gflag[gr*FW + t]) < GN) __builtin_amdgcn_s_sleep(1);
        if (t >= 5) {
          unsigned tgt = AK * (unsigned)(t - 4);
          while (ldu(&g_aprog[gr]) < tgt) __builtin_amdgcn_s_sleep(1);
        }
      }
      __syncthreads();
      const int sp = (t + 5) % HSLOTS;
      for (int s = 0; s < S; ++s)
        ht[s*516 + kq*64 + lane] =
            ldg_sys(&g_h[((size_t)sp*NSEQ + sbase + s)*EH + kq*64 + lane]);
      if (tran) gemm2<8,8>(wpl, ht, part, kq, clbase);
      else      gemm2<8,4>(wpl, ht, part, kq, clbase);
      __syncthreads();
      const int so = t % HSLOTS;
      if (tran) {
        #pragma unroll
        for (int ch2 = 0; ch2 < 2; ++ch2) {
          int i = tid + ch2*512; int jl = i & 127, s = i >> 7;
          float u[4];
          #pragma unroll
          for (int g4 = 0; g4 < 4; ++g4) {
            float v = ch2 ? xpB[g4] : xpA[g4];
            #pragma unroll
            for (int q = 0; q < 4; ++q) v += part[(size_t)(q*S + s)*516 + g4*128 + jl];
            u[g4] = v;
          }
          float cv = cb[s*128 + jl];
          float cn = sigm(u[1])*cv + sigm(u[0])*tanhf(u[2]);
          float hn = sigm(u[3])*tanhf(cn);
          cb[s*128 + jl] = cn;
          stg_sys(&g_h[((size_t)so*NSEQ + sbase + s)*EH + cgx*128 + jl], hn);
        }
      } else {
        int jl = tid & 63, s = tid >> 6;
        float u[4];
        #pragma unroll
        for (int g4 = 0; g4 < 4; ++g4) {
          float v = xpA[g4];
          #pragma unroll
          for (int q = 0; q < 4; ++q) v += part[(size_t)(q*S + s)*260 + g4*64 + jl];
          u[g4] = v;
        }
        float cv = cb[s*64 + jl];
        float cn = sigm(u[1])*cv + sigm(u[0])*tanhf(u[2]);
        float hn = sigm(u[3])*tanhf(cn);
        cb[s*64 + jl] = cn;
        stg_sys(&g_h[((size_t)so*NSEQ + sbase + s)*EH + cgx*128 + halfx*64 + jl], hn);
      }
      __syncthreads();   // drains vmcnt(0): h stores at L3 before flag RMW
      if (tid == 0) atomicAdd(&g_gflag[gr*FW + t + 1], 1u);
    }
  } else {
    // ================= attn block =================
    for (int t = 1; t <= Ts + 1; ++t) {
      float* hcur  = (t & 1) ? htB : ht;
      float* hprev = (t & 1) ? ht : htB;
      if (tid == 0) {
        if (t <= Ts)
          while (ldu(&g_gflag[gr*FW + t]) < GN) __builtin_amdgcn_s_sleep(1);
        if (!tran && t >= 2)
          while (ldu(&g_sflag[grd*FW + (t - 1)]) < 4u) __builtin_amdgcn_s_sleep(1);
      }
      __syncthreads();
      const int sp = (t + 5) % HSLOTS;
      if (t <= Ts) {
        for (int s = 0; s < S; ++s)
          hcur[s*516 + kq*64 + lane] =
              ldg_sys(&g_h[((size_t)sp*NSEQ + sbase + s)*EH + kq*64 + lane]);
      }
      if (t >= 2 && tid < S) {
        int s = tid;
        if ((float)(t - 2) < lenb[s]) {
          float sv = tran ? scr[(t & 1)*8 + s]
                          : ldg_sys(&g_sc[(sbase + s - NTRAN)*260 + (t - 2)]);
          float mo = ml[s*2], lo = ml[s*2+1];
          float mn = fmaxf(mo, sv);
          float a = expf(mo - mn), e = expf(sv - mn);
          alb[s*2] = a; alb[s*2+1] = e;
          ml[s*2] = mn; ml[s*2+1] = lo*a + e;
        } else { alb[s*2] = 1.0f; alb[s*2+1] = 0.0f; }
      }
      __syncthreads();
      if (t <= Ts) {
        if (tran) gemm2<8,8>(wpl, hcur, part, kq, clbase);
        else      gemm2<8,2>(wpl, hcur, part, kq, clbase);
      }
      if (t >= 2) {
        for (int i = tid; i < S*DW; i += 512) {
          int s = tran ? (i >> 9) : (i >> 7);
          int dl = i & (DW - 1);
          float a = alb[s*2], e = alb[s*2+1];
          if (!(a == 1.0f && e == 0.0f)) {
            float hv = hprev[s*516 + colbase + dl];
            cb[s*DW + dl] = cb[s*DW + dl]*a + e*hv;
          }
        }
      }
      __syncthreads();
      if (tid == 0) atomicAdd(&g_aprog[gr], 1u);
      if (t <= Ts) {
        for (int i = tid; i < CW*S; i += 512) {
          int c = i & (CW - 1);
          int s = tran ? (i >> 9) : (i >> 7);
          float u = ab[colbase + c];
          #pragma unroll
          for (int q = 0; q < 4; ++q) u += part[(size_t)(q*S + s)*PW + c];
          float p = tanhf(u) * sw[colbase + c];
          part[(size_t)s*PW + c] = p;
        }
        __syncthreads();
        if (w < S) {
          int s = w;
          float p = 0.0f;
          for (int j = 0; j < CW/64; ++j) p += part[(size_t)s*PW + j*64 + lane];
          #pragma unroll
          for (int off = 32; off >= 1; off >>= 1) p += __shfl_xor(p, off, 64);
          if (lane == 0) {
            if (tran) scr[((t - 1) & 1)*8 + s] = p + sb;
            else atomicAdd(&g_sc[(sbase + s - NTRAN)*260 + (t - 1)],
                           p + (q4 == 0 ? sb : 0.0f));
          }
        }
        if (!tran) {
          __syncthreads();
          if (tid == 0) atomicAdd(&g_sflag[grd*FW + t], 1u);
        }
      }
    }
    // epilogue: pooled
    for (int i = tid; i < S*DW; i += 512) {
      int s = tran ? (i >> 9) : (i >> 7);
      int dl = i & (DW - 1);
      float v = cb[s*DW + dl] / ml[s*2+1];
      if (tran) v = tanhf(v);
      g_pool[(size_t)(sbase + s)*EH + colbase + dl] = v;
    }
  }
}

// ---------------- per-batch cosine terms + loss ----------------
__global__ __launch_bounds__(256) void loss_partial() {
  __shared__ float red[5][4];
  int b = blockIdx.x, tid = threadIdx.x;
  float p[5] = {0.f, 0.f, 0.f, 0.f, 0.f};
  for (int j = tid; j < EH; j += 256) {
    float mx = -3.0e38f;
    #pragma unroll
    for (int bl = 0; bl < 8; bl++) mx = fmaxf(mx, g_pool[(b*8 + bl)*EH + j]);
    float da = g_pool[(NTRAN + b)*EH + j];
    float dn = g_pool[(NTRAN + 32 + b)*EH + j];
    p[0] += mx*mx; p[1] += da*da; p[2] += dn*dn; p[3] += mx*da; p[4] += mx*dn;
  }
  int lane = tid & 63, w = tid >> 6;
  #pragma unroll
  for (int i = 0; i < 5; i++) {
    float v = p[i];
    for (int off = 32; off >= 1; off >>= 1) v += __shfl_xor(v, off, 64);
    if (lane == 0) red[i][w] = v;
  }
  __syncthreads();
  if (tid == 0) {
    float cc = red[0][0]+red[0][1]+red[0][2]+red[0][3];
    float aa = red[1][0]+red[1][1]+red[1][2]+red[1][3];
    float nn = red[2][0]+red[2][1]+red[2][2]+red[2][3];
    float ca = red[3][0]+red[3][1]+red[3][2]+red[3][3];
    float cn = red[4][0]+red[4][1]+red[4][2]+red[4][3];
    float ncr = fmaxf(sqrtf(cc), 1e-8f);
    float nda = fmaxf(sqrtf(aa), 1e-8f);
    float ndn = fmaxf(sqrtf(nn), 1e-8f);
    float simA = ca / (ncr * nda);
    float simN = cn / (ncr * ndn);
    float term = fmaxf(0.05f - simA + simN, 1e-6f);
    atomicAdd(&g_loss, term * (1.0f / 32.0f));
  }
}

__global__ void write_out(float* __restrict__ out) {
  if (threadIdx.x == 0 && blockIdx.x == 0) out[0] = g_loss;
}

extern "C" void kernel_launch(void* const* d_in, const int* in_sizes, int n_in,
                              void* d_out, int out_size, void* d_ws, size_t ws_size,
                              hipStream_t stream) {
  (void)in_sizes; (void)n_in; (void)out_size; (void)d_ws; (void)ws_size;
  const int*   tran   = (const int*)d_in[0];
  const int*   tbl    = (const int*)d_in[2];
  const int*   da_tok = (const int*)d_in[3];
  const int*   dal    = (const int*)d_in[4];
  const int*   dn_tok = (const int*)d_in[5];
  const int*   dnl    = (const int*)d_in[6];
  const float* emb    = (const float*)d_in[7];
  const float* wih_t  = (const float*)d_in[8];
  const float* whh_t  = (const float*)d_in[9];
  const float* b_t    = (const float*)d_in[10];
  const float* wih_d  = (const float*)d_in[11];
  const float* whh_d  = (const float*)d_in[12];
  const float* b_d    = (const float*)d_in[13];
  const float* aw_t   = (const float*)d_in[14];
  const float* ab_t   = (const float*)d_in[15];
  const float* sw_t   = (const float*)d_in[16];
  const float* sb_t   = (const float*)d_in[17];
  const float* aw_d   = (const float*)d_in[18];
  const float* ab_d   = (const float*)d_in[19];
  const float* sw_d   = (const float*)d_in[20];
  const float* sb_d   = (const float*)d_in[21];

  init_state<<<(NSEQ*EH + 255)/256, 256, 0, stream>>>();
  build_wbx<<<(2*2048*512 + 255)/256, 256, 0, stream>>>(wih_t, wih_d);
  build_wt2<<<(2*5*512*512 + 255)/256, 256, 0, stream>>>(whh_t, whh_d, aw_t, aw_d);
  pregather<<<XROWS, 128, 0, stream>>>(tran, da_tok, dn_tok, emb);
  xproj_mfma<<<(XROWS/256)*8, 512, 0, stream>>>(b_t, b_d);

  persist<<<256, 512, 0, stream>>>(tbl, dal, dnl,
      ab_t, ab_d, sw_t, sw_d, sb_t, sb_d);

  loss_partial<<<32, 256, 0, stream>>>();
  write_out<<<1, 64, 0, stream>>>((float*)d_out);
}

// Round 15
// 2962.552 us; speedup vs baseline: 1.1481x; 1.1481x over previous
//
#include <hip/hip_runtime.h>
#include <hip/hip_bf16.h>

#define NSEQ 320
#define NTRAN 256
#define TT 128
#define TDOC 256
#define EH 512
#define XR_TRAN (NTRAN*TT)            // 32768
#define XROWS (XR_TRAN + 64*TDOC)     // 49152
#define HSLOTS 6
#define FW 264

typedef __attribute__((ext_vector_type(8))) short bf16x8v;
typedef __attribute__((ext_vector_type(4))) float f32x4v;

// ---- module-global scratch ----
__device__ __align__(16) unsigned short g_xb [(size_t)XROWS*EH];     // bf16 embeddings [row][512]
__device__ __align__(16) unsigned short g_wbx[2*2048*512];           // bf16 wih [path][col][k]
__device__ __align__(16) unsigned short g_w2b[2*5*512*512];          // bf16 recurrence W [path][cg][k][col]
__device__ float g_xp[(size_t)XROWS*2048];  // xproj+bias, gate-interleaved cols (fp32)
__device__ float g_h [HSLOTS*NSEQ*EH];      // h ring — system-scope accessed
__device__ float g_sc[64*260];              // doc scores
__device__ float g_pool[NSEQ*EH];
__device__ float g_loss;
__device__ unsigned g_gflag[48*FW];
__device__ unsigned g_sflag[16*FW];
__device__ unsigned g_aprog[48];

__device__ __forceinline__ float sigm(float x) { return 1.0f / (1.0f + expf(-x)); }

__device__ __forceinline__ float ldg_sys(const float* p) {
  return __hip_atomic_load(p, __ATOMIC_RELAXED, __HIP_MEMORY_SCOPE_SYSTEM);
}
__device__ __forceinline__ void stg_sys(float* p, float v) {
  __hip_atomic_store(p, v, __ATOMIC_RELAXED, __HIP_MEMORY_SCOPE_SYSTEM);
}
__device__ __forceinline__ unsigned ldu(const unsigned* p) {
  return __hip_atomic_load(p, __ATOMIC_RELAXED, __HIP_MEMORY_SCOPE_AGENT);
}
__device__ __forceinline__ unsigned short f2b(float f) {
  __hip_bfloat16 h = __float2bfloat16(f);
  return *reinterpret_cast<unsigned short*>(&h);
}

// ---------------- init per call ----------------
__global__ __launch_bounds__(256) void init_state() {
  int i = blockIdx.x*256 + threadIdx.x;
  if (i < NSEQ*EH) g_h[5*NSEQ*EH + i] = 0.0f;
  if (i < 64*260) g_sc[i] = 0.0f;
  if (i < 48*FW) g_gflag[i] = ((i % FW) == 0) ? 4u : 0u;
  if (i < 16*FW) g_sflag[i] = 0u;
  if (i < 48) g_aprog[i] = 0u;
  if (i == 0) g_loss = 0.0f;
}

// ---------------- bf16 xproj weights: [path][col][k] ----------------
__global__ __launch_bounds__(256) void build_wbx(
    const float* __restrict__ wih_t, const float* __restrict__ wih_d) {
  int idx = blockIdx.x*256 + threadIdx.x;
  if (idx >= 2*2048*512) return;
  int p = idx / (2048*512); int rem = idx % (2048*512);
  const float* wih = p ? wih_d : wih_t;
  g_wbx[idx] = f2b(wih[rem]);
}

// ---------------- bf16 recurrence weights: [path][cg][k][col512] ----------------
__global__ __launch_bounds__(256) void build_wt2(
    const float* __restrict__ whh_t, const float* __restrict__ whh_d,
    const float* __restrict__ aw_t,  const float* __restrict__ aw_d) {
  int idx = blockIdx.x*256 + threadIdx.x;
  if (idx >= 2*5*512*512) return;
  int p  = idx / (5*512*512); int rem = idx % (5*512*512);
  int cg = rem / (512*512);   int r2  = rem % (512*512);
  int k  = r2 >> 9;           int c   = r2 & 511;
  float v;
  if (cg < 4) {
    int r = (c >> 7)*512 + cg*128 + (c & 127);
    const float* whh = p ? whh_d : whh_t;
    v = whh[r*512 + k];
  } else {
    const float* aw = p ? aw_d : aw_t;
    v = aw[c*512 + k];
  }
  g_w2b[((size_t)(p*5 + cg)*512 + k)*512 + c] = f2b(v);
}

// ---------------- pre-gather embeddings -> bf16 ----------------
__global__ __launch_bounds__(128) void pregather(
    const int* __restrict__ tran, const int* __restrict__ da_tok,
    const int* __restrict__ dn_tok, const float* __restrict__ emb) {
  int row = blockIdx.x;
  int tok;
  if (row < XR_TRAN) tok = tran[row];
  else {
    int q = row - XR_TRAN;
    tok = (q < 32*TDOC) ? da_tok[q] : dn_tok[q - 32*TDOC];
  }
  const float4* src = (const float4*)&emb[(size_t)tok*EH];
  float4 v = src[threadIdx.x];
  uint2 o;
  o.x = (unsigned)f2b(v.x) | ((unsigned)f2b(v.y) << 16);
  o.y = (unsigned)f2b(v.z) | ((unsigned)f2b(v.w) << 16);
  ((uint2*)&g_xb[(size_t)row*EH])[threadIdx.x] = o;
}

// ---------------- MFMA bf16 xproj (proven in R13) ----------------
__global__ __launch_bounds__(512, 2) void xproj_mfma(
    const float* __restrict__ b_t, const float* __restrict__ b_d) {
  __shared__ short As[2][256*32];
  __shared__ short Bs[2][256*32];
  const int bid = blockIdx.x;
  const int mt = bid >> 3, ntb = bid & 7;
  const size_t mb = (size_t)mt * 256; const int nb = ntb * 256;
  const bool tp = (mb < XR_TRAN);
  const size_t wboff = (tp ? 0 : (size_t)2048*512);
  const float* __restrict__ bias = tp ? b_t : b_d;
  const int tid = threadIdx.x;
  const int l = tid & 63, w = tid >> 6;
  const int mw = w >> 2, nw = w & 3;

  f32x4v acc[8][4];
  #pragma unroll
  for (int m2 = 0; m2 < 8; ++m2)
    #pragma unroll
    for (int n2 = 0; n2 < 4; ++n2) acc[m2][n2] = (f32x4v){0.f, 0.f, 0.f, 0.f};

  uint4 rA[2], rB[2];
  auto stage_load = [&](int k0) {
    #pragma unroll
    for (int i = 0; i < 2; ++i) {
      int u = i*512 + tid;
      rA[i] = *(const uint4*)&g_xb[(mb + (u >> 2))*512 + k0 + (u & 3)*8];
      rB[i] = *(const uint4*)&g_wbx[wboff + (size_t)(nb + (u >> 2))*512 + k0 + (u & 3)*8];
    }
  };
  auto stage_write = [&](int buf) {
    #pragma unroll
    for (int i = 0; i < 2; ++i) {
      int u = i*512 + tid;
      *(uint4*)&As[buf][u*8] = rA[i];
      *(uint4*)&Bs[buf][u*8] = rB[i];
    }
  };

  stage_load(0); stage_write(0); __syncthreads();
  for (int ks = 0; ks < 16; ++ks) {
    const int buf = ks & 1;
    if (ks < 15) stage_load((ks + 1)*32);
    bf16x8v aF[8], bF[4];
    #pragma unroll
    for (int m2 = 0; m2 < 8; ++m2)
      aF[m2] = *(const bf16x8v*)&As[buf][(mw*128 + m2*16 + (l & 15))*32 + (l >> 4)*8];
    #pragma unroll
    for (int n2 = 0; n2 < 4; ++n2)
      bF[n2] = *(const bf16x8v*)&Bs[buf][(nw*64 + n2*16 + (l & 15))*32 + (l >> 4)*8];
    #pragma unroll
    for (int m2 = 0; m2 < 8; ++m2)
      #pragma unroll
      for (int n2 = 0; n2 < 4; ++n2)
        acc[m2][n2] = __builtin_amdgcn_mfma_f32_16x16x32_bf16(aF[m2], bF[n2], acc[m2][n2], 0, 0, 0);
    __syncthreads();
    if (ks < 15) stage_write(buf ^ 1);
    __syncthreads();
  }

  #pragma unroll
  for (int n2 = 0; n2 < 4; ++n2) {
    const int colg = nb + nw*64 + n2*16 + (l & 15);
    const int col2 = ((colg & 511) >> 7)*512 + (colg >> 9)*128 + (colg & 127);
    const float bv = bias[colg];
    #pragma unroll
    for (int m2 = 0; m2 < 8; ++m2) {
      #pragma unroll
      for (int r = 0; r < 4; ++r) {
        size_t row = mb + mw*128 + m2*16 + (l >> 4)*4 + r;
        g_xp[row*2048 + col2] = acc[m2][n2][r] + bv;
      }
    }
  }
}

// ---------------- recurrence GEMM (R13-proven: contiguous CPL*lane cols) ----------
template<int S, int CPL>
__device__ __forceinline__ void gemm2(const unsigned short* __restrict__ wsl,
                                      const float* __restrict__ ht,
                                      float* __restrict__ part,
                                      int kq, int lane) {
  constexpr int PW = CPL*64 + 4;
  float acc[CPL][S];
  #pragma unroll
  for (int c = 0; c < CPL; ++c)
    #pragma unroll
    for (int s = 0; s < S; ++s) acc[c][s] = 0.0f;
  const unsigned short* wp = wsl + (size_t)(kq*64)*512 + CPL*lane;
  const float* hb = ht + kq*64;
  #pragma unroll 2
  for (int k4 = 0; k4 < 16; ++k4) {
    float4 hv[S];
    #pragma unroll
    for (int s = 0; s < S; ++s) hv[s] = *(const float4*)&hb[s*516 + k4*4];
    #pragma unroll
    for (int i4 = 0; i4 < 4; ++i4) {
      float wf[CPL];
      if constexpr (CPL == 8) {
        uint4 wv = *(const uint4*)(wp + (size_t)(k4*4 + i4)*512);
        wf[0] = __uint_as_float(wv.x << 16); wf[1] = __uint_as_float(wv.x & 0xFFFF0000u);
        wf[2] = __uint_as_float(wv.y << 16); wf[3] = __uint_as_float(wv.y & 0xFFFF0000u);
        wf[4] = __uint_as_float(wv.z << 16); wf[5] = __uint_as_float(wv.z & 0xFFFF0000u);
        wf[6] = __uint_as_float(wv.w << 16); wf[7] = __uint_as_float(wv.w & 0xFFFF0000u);
      } else {
        uint2 wv = *(const uint2*)(wp + (size_t)(k4*4 + i4)*512);
        wf[0] = __uint_as_float(wv.x << 16); wf[1] = __uint_as_float(wv.x & 0xFFFF0000u);
        wf[2] = __uint_as_float(wv.y << 16); wf[3] = __uint_as_float(wv.y & 0xFFFF0000u);
      }
      #pragma unroll
      for (int s = 0; s < S; ++s) {
        float h = ((const float*)&hv[s])[i4];
        #pragma unroll
        for (int c = 0; c < CPL; ++c) acc[c][s] = fmaf(wf[c], h, acc[c][s]);
      }
    }
  }
  if (kq < 4) {
    #pragma unroll
    for (int s = 0; s < S; ++s)
      #pragma unroll
      for (int c = 0; c < CPL; ++c)
        part[(size_t)(kq*S + s)*PW + CPL*lane + c] = acc[c][s];
  }
  __syncthreads();
  if (kq >= 4) {
    const int q = kq - 4;
    #pragma unroll
    for (int s = 0; s < S; ++s)
      #pragma unroll
      for (int c = 0; c < CPL; ++c)
        part[(size_t)(q*S + s)*PW + CPL*lane + c] += acc[c][s];
  }
}

// ---------------- persistent recurrence kernel (R13 + uniform-poll gate entry) ------
// tran (x<5): 32 groups x (4 gate + 1 attn), S=8, 128 steps.
// doc (x 5..7): 16 groups x (4 gate 512col + 2 attn halves 256col/dim), S=4, 256 steps.
// Gate blocks: ALL-LANE uniform flag polling, NO entry barrier — after the poll,
// ht staging and gemm round-1 are wave-private; cross-wave ordering comes from
// gemm2's internal barrier + the previous step's post-epilogue barrier; flag
// conditions are monotonic so independent per-wave waits are safe.
// Attn blocks keep the entry barrier (scr ring has a cross-wave step dependence).
__global__ __launch_bounds__(512, 2) void persist(
    const int* __restrict__ tbl, const int* __restrict__ dal, const int* __restrict__ dnl,
    const float* __restrict__ ab_t, const float* __restrict__ ab_d,
    const float* __restrict__ sw_t, const float* __restrict__ sw_d,
    const float* __restrict__ sb_t, const float* __restrict__ sb_d) {
  __shared__ float sm[28920];   // 115.7 KB -> 1 block/CU (co-residency required)
  float* part = sm;
  float* ht   = sm + 16512;
  float* cb   = sm + 20640;
  float* scr  = sm + 24736;
  float* ml   = sm + 24752;
  float* lenb = sm + 24768;
  float* alb  = sm + 24776;
  float* htB  = sm + 24792;

  const int b = blockIdx.x, tid = threadIdx.x;
  const int x = b & 7, m = b >> 3;
  bool tran; int cg, nt;
  if (x < 5) { tran = true; cg = x; nt = m; }
  else { int slot = (x - 5)*32 + m; tran = false; cg = slot >> 4; nt = slot & 15; }
  const int S     = tran ? 8 : 4;
  const int Ts    = tran ? TT : TDOC;
  const int sbase = tran ? nt*8 : NTRAN + nt*4;
  const bool isattn = (cg >= 4);
  const int gr = tran ? nt : 32 + nt;
  const unsigned AK = tran ? 1u : 2u;
  const int colbase = tran ? 0 : (cg - 4) * 256;
  const int wslice  = isattn ? 4 : cg;
  const unsigned short* __restrict__ wsl =
      g_w2b + (size_t)((tran ? 0 : 5) + wslice)*512*512 + (isattn ? colbase : 0);
  const float* __restrict__ ab  = tran ? ab_t : ab_d;
  const float* __restrict__ sw  = tran ? sw_t : sw_d;
  const float  sb = tran ? sb_t[0] : sb_d[0];

  for (int i = tid; i < 4096; i += 512) cb[i] = 0.0f;
  if (tid < S) {
    ml[tid*2] = -3.0e38f; ml[tid*2+1] = 0.0f;
    int s = sbase + tid;
    int len = tran ? tbl[s] : (s < NTRAN+32 ? dal[s-NTRAN] : dnl[s-NTRAN-32]);
    lenb[tid] = (float)len;
  }
  __syncthreads();

  const int lane = tid & 63, kq = tid >> 6;
  const int w = kq;
  const int PW = tran ? 516 : (isattn ? 260 : 516);
  const int CW = isattn ? (tran ? 512 : 256) : 0;
  const int DW = isattn ? (tran ? 512 : 256) : 0;

  if (!isattn) {
    // ================= gate block =================
    for (int t = 0; t < Ts; ++t) {
      float xpA[4], xpB[4];
      {
        int i = tid; int jl = i & 127, s = i >> 7;
        size_t row = tran ? (size_t)(sbase + s)*TT + t
                          : (size_t)XR_TRAN + (size_t)(sbase + s - NTRAN)*TDOC + t;
        const float* xr = &g_xp[row*2048 + cg*512];
        #pragma unroll
        for (int g4 = 0; g4 < 4; ++g4) xpA[g4] = xr[g4*128 + jl];
      }
      if (tran) {
        int i = tid + 512; int jl = i & 127, s = i >> 7;
        size_t row = (size_t)(sbase + s)*TT + t;
        const float* xr = &g_xp[row*2048 + cg*512];
        #pragma unroll
        for (int g4 = 0; g4 < 4; ++g4) xpB[g4] = xr[g4*128 + jl];
      }
      // all-lane uniform polls (broadcast load, uniform branch) — no entry barrier
      if (t > 0)
        while (ldu(&g_gflag[gr*FW + t]) < 4u) __builtin_amdgcn_s_sleep(1);
      if (t >= 5) {
        unsigned tgt = AK * (unsigned)(t - 4);
        while (ldu(&g_aprog[gr]) < tgt) __builtin_amdgcn_s_sleep(1);
      }
      const int sp = (t + 5) % HSLOTS;
      for (int s = 0; s < S; ++s)
        ht[s*516 + kq*64 + lane] =
            ldg_sys(&g_h[((size_t)sp*NSEQ + sbase + s)*EH + kq*64 + lane]);
      if (tran) gemm2<8,8>(wsl, ht, part, kq, lane);
      else      gemm2<4,8>(wsl, ht, part, kq, lane);
      __syncthreads();
      const int so = t % HSLOTS;
      {
        int i = tid; int jl = i & 127, s = i >> 7;
        float u[4];
        #pragma unroll
        for (int g4 = 0; g4 < 4; ++g4) {
          float v = xpA[g4];
          #pragma unroll
          for (int q = 0; q < 4; ++q) v += part[(size_t)(q*S + s)*516 + g4*128 + jl];
          u[g4] = v;
        }
        float cv = cb[s*128 + jl];
        float cn = sigm(u[1])*cv + sigm(u[0])*tanhf(u[2]);
        float hn = sigm(u[3])*tanhf(cn);
        cb[s*128 + jl] = cn;
        stg_sys(&g_h[((size_t)so*NSEQ + sbase + s)*EH + cg*128 + jl], hn);
      }
      if (tran) {
        int i = tid + 512; int jl = i & 127, s = i >> 7;
        float u[4];
        #pragma unroll
        for (int g4 = 0; g4 < 4; ++g4) {
          float v = xpB[g4];
          #pragma unroll
          for (int q = 0; q < 4; ++q) v += part[(size_t)(q*S + s)*516 + g4*128 + jl];
          u[g4] = v;
        }
        float cv = cb[s*128 + jl];
        float cn = sigm(u[1])*cv + sigm(u[0])*tanhf(u[2]);
        float hn = sigm(u[3])*tanhf(cn);
        cb[s*128 + jl] = cn;
        stg_sys(&g_h[((size_t)so*NSEQ + sbase + s)*EH + cg*128 + jl], hn);
      }
      __syncthreads();   // drains vmcnt(0): h stores at L3 before flag RMW
      if (tid == 0) atomicAdd(&g_gflag[gr*FW + t + 1], 1u);
    }
  } else {
    // ================= attn block (unchanged from R13) =================
    for (int t = 1; t <= Ts + 1; ++t) {
      float* hcur  = (t & 1) ? htB : ht;
      float* hprev = (t & 1) ? ht : htB;
      if (tid == 0) {
        if (t <= Ts)
          while (ldu(&g_gflag[gr*FW + t]) < 4u) __builtin_amdgcn_s_sleep(1);
        if (!tran && t >= 2)
          while (ldu(&g_sflag[nt*FW + (t - 1)]) < 2u) __builtin_amdgcn_s_sleep(1);
      }
      __syncthreads();
      const int sp = (t + 5) % HSLOTS;
      if (t <= Ts) {
        for (int s = 0; s < S; ++s)
          hcur[s*516 + kq*64 + lane] =
              ldg_sys(&g_h[((size_t)sp*NSEQ + sbase + s)*EH + kq*64 + lane]);
      }
      if (t >= 2 && tid < S) {
        int s = tid;
        if ((float)(t - 2) < lenb[s]) {
          float sv = tran ? scr[(t & 1)*8 + s]
                          : ldg_sys(&g_sc[(sbase + s - NTRAN)*260 + (t - 2)]);
          float mo = ml[s*2], lo = ml[s*2+1];
          float mn = fmaxf(mo, sv);
          float a = expf(mo - mn), e = expf(sv - mn);
          alb[s*2] = a; alb[s*2+1] = e;
          ml[s*2] = mn; ml[s*2+1] = lo*a + e;
        } else { alb[s*2] = 1.0f; alb[s*2+1] = 0.0f; }
      }
      __syncthreads();
      if (t <= Ts) {
        if (tran) gemm2<8,8>(wsl, hcur, part, kq, lane);
        else      gemm2<4,4>(wsl, hcur, part, kq, lane);
      }
      if (t >= 2) {
        for (int i = tid; i < S*DW; i += 512) {
          int s = tran ? (i >> 9) : (i >> 8);
          int dl = i & (DW - 1);
          float a = alb[s*2], e = alb[s*2+1];
          if (!(a == 1.0f && e == 0.0f)) {
            float hv = hprev[s*516 + colbase + dl];
            cb[s*DW + dl] = cb[s*DW + dl]*a + e*hv;
          }
        }
      }
      __syncthreads();
      if (tid == 0) atomicAdd(&g_aprog[gr], 1u);
      if (t <= Ts) {
        for (int i = tid; i < CW*S; i += 512) {
          int c = i & (CW - 1);
          int s = tran ? (i >> 9) : (i >> 8);
          float u = ab[colbase + c];
          #pragma unroll
          for (int q = 0; q < 4; ++q) u += part[(size_t)(q*S + s)*PW + c];
          float p = tanhf(u) * sw[colbase + c];
          part[(size_t)s*PW + c] = p;
        }
        __syncthreads();
        if (w < S) {
          int s = w;
          float p = 0.0f;
          for (int j = 0; j < CW/64; ++j) p += part[(size_t)s*PW + j*64 + lane];
          #pragma unroll
          for (int off = 32; off >= 1; off >>= 1) p += __shfl_xor(p, off, 64);
          if (lane == 0) {
            if (tran) scr[((t - 1) & 1)*8 + s] = p + sb;
            else atomicAdd(&g_sc[(sbase + s - NTRAN)*260 + (t - 1)],
                           p + (cg == 4 ? sb : 0.0f));
          }
        }
        if (!tran) {
          __syncthreads();
          if (tid == 0) atomicAdd(&g_sflag[nt*FW + t], 1u);
        }
      }
    }
    // epilogue: pooled
    for (int i = tid; i < S*DW; i += 512) {
      int s = tran ? (i >> 9) : (i >> 8);
      int dl = i & (DW - 1);
      float v = cb[s*DW + dl] / ml[s*2+1];
      if (tran) v = tanhf(v);
      g_pool[(size_t)(sbase + s)*EH + colbase + dl] = v;
    }
  }
}

// ---------------- per-batch cosine terms + loss ----------------
__global__ __launch_bounds__(256) void loss_partial() {
  __shared__ float red[5][4];
  int b = blockIdx.x, tid = threadIdx.x;
  float p[5] = {0.f, 0.f, 0.f, 0.f, 0.f};
  for (int j = tid; j < EH; j += 256) {
    float mx = -3.0e38f;
    #pragma unroll
    for (int bl = 0; bl < 8; bl++) mx = fmaxf(mx, g_pool[(b*8 + bl)*EH + j]);
    float da = g_pool[(NTRAN + b)*EH + j];
    float dn = g_pool[(NTRAN + 32 + b)*EH + j];
    p[0] += mx*mx; p[1] += da*da; p[2] += dn*dn; p[3] += mx*da; p[4] += mx*dn;
  }
  int lane = tid & 63, w = tid >> 6;
  #pragma unroll
  for (int i = 0; i < 5; i++) {
    float v = p[i];
    for (int off = 32; off >= 1; off >>= 1) v += __shfl_xor(v, off, 64);
    if (lane == 0) red[i][w] = v;
  }
  __syncthreads();
  if (tid == 0) {
    float cc = red[0][0]+red[0][1]+red[0][2]+red[0][3];
    float aa = red[1][0]+red[1][1]+red[1][2]+red[1][3];
    float nn = red[2][0]+red[2][1]+red[2][2]+red[2][3];
    float ca = red[3][0]+red[3][1]+red[3][2]+red[3][3];
    float cn = red[4][0]+red[4][1]+red[4][2]+red[4][3];
    float ncr = fmaxf(sqrtf(cc), 1e-8f);
    float nda = fmaxf(sqrtf(aa), 1e-8f);
    float ndn = fmaxf(sqrtf(nn), 1e-8f);
    float simA = ca / (ncr * nda);
    float simN = cn / (ncr * ndn);
    float term = fmaxf(0.05f - simA + simN, 1e-6f);
    atomicAdd(&g_loss, term * (1.0f / 32.0f));
  }
}

__global__ void write_out(float* __restrict__ out) {
  if (threadIdx.x == 0 && blockIdx.x == 0) out[0] = g_loss;
}

extern "C" void kernel_launch(void* const* d_in, const int* in_sizes, int n_in,
                              void* d_out, int out_size, void* d_ws, size_t ws_size,
                              hipStream_t stream) {
  (void)in_sizes; (void)n_in; (void)out_size; (void)d_ws; (void)ws_size;
  const int*   tran   = (const int*)d_in[0];
  const int*   tbl    = (const int*)d_in[2];
  const int*   da_tok = (const int*)d_in[3];
  const int*   dal    = (const int*)d_in[4];
  const int*   dn_tok = (const int*)d_in[5];
  const int*   dnl    = (const int*)d_in[6];
  const float* emb    = (const float*)d_in[7];
  const float* wih_t  = (const float*)d_in[8];
  const float* whh_t  = (const float*)d_in[9];
  const float* b_t    = (const float*)d_in[10];
  const float* wih_d  = (const float*)d_in[11];
  const float* whh_d  = (const float*)d_in[12];
  const float* b_d    = (const float*)d_in[13];
  const float* aw_t   = (const float*)d_in[14];
  const float* ab_t   = (const float*)d_in[15];
  const float* sw_t   = (const float*)d_in[16];
  const float* sb_t   = (const float*)d_in[17];
  const float* aw_d   = (const float*)d_in[18];
  const float* ab_d   = (const float*)d_in[19];
  const float* sw_d   = (const float*)d_in[20];
  const float* sb_d   = (const float*)d_in[21];

  init_state<<<(NSEQ*EH + 255)/256, 256, 0, stream>>>();
  build_wbx<<<(2*2048*512 + 255)/256, 256, 0, stream>>>(wih_t, wih_d);
  build_wt2<<<(2*5*512*512 + 255)/256, 256, 0, stream>>>(whh_t, whh_d, aw_t, aw_d);
  pregather<<<XROWS, 128, 0, stream>>>(tran, da_tok, dn_tok, emb);
  xproj_mfma<<<(XROWS/256)*8, 512, 0, stream>>>(b_t, b_d);

  persist<<<256, 512, 0, stream>>>(tbl, dal, dnl,
      ab_t, ab_d, sw_t, sw_d, sb_t, sb_d);

  loss_partial<<<32, 256, 0, stream>>>();
  write_out<<<1, 64, 0, stream>>>((float*)d_out);
}